// Round 4
// baseline (305.722 us; speedup 1.0000x reference)
//
#include <hip/hip_runtime.h>
#include <hip/hip_bf16.h>

#define K_NEIGH 32
#define D_FEAT  128
#define WPB     4        // waves (batch elements) per 256-thread block
#define RSTRIDE 65       // dwords per LDS row slot (64 bf16x2 + 1 pad)

__device__ __forceinline__ float readlane_f(float v, int l) {
    return __int_as_float(__builtin_amdgcn_readlane(__float_as_int(v), l));
}

// One wave per batch element. Lane l owns dims {2l, 2l+1} (float2).
// Rows are consumed into dot/norm partials on arrival AND parked in LDS as
// packed bf16 (so the mean phase never re-gathers from global).
// Reduction: 6-step fold (lane l ends holding sim of row l>>1). Top-k is
// computed entirely in fp32 -> selection bit-exact vs reference; only the
// averaged feature values are bf16-rounded (abs err ~0.009 << 0.033 thr).
__global__ __launch_bounds__(256, 4) void intra_agg_kernel(
    const float* __restrict__ features,
    const int*   __restrict__ nodes,
    const int*   __restrict__ neighs,
    const int*   __restrict__ num_sample_p,
    float*       __restrict__ out,
    int batch)
{
    __shared__ unsigned s_rows[WPB][K_NEIGH * RSTRIDE];   // 8320 B / wave

    const int tid  = blockIdx.x * blockDim.x + threadIdx.x;
    const int lane = threadIdx.x & 63;
    const int w    = threadIdx.x >> 6;
    int b = tid >> 6;
    if (b >= batch) return;
    b = __builtin_amdgcn_readfirstlane(b);   // force scalar index/addr path

    const int  ns = *num_sample_p;
    const int* nb = neighs + (size_t)b * K_NEIGH;

    // Center fragment (coalesced 512B across the wave) + ||center||.
    const int    cnode = nodes[b];
    const float2 c2 = ((const float2*)(features + (size_t)cnode * D_FEAT))[lane];
    float cc = c2.x * c2.x + c2.y * c2.y;
    #pragma unroll
    for (int m = 32; m >= 1; m >>= 1) cc += __shfl_xor(cc, m);
    const float cn = sqrtf(cc);

    // Load all 32 rows (independent, coalesced); consume into partials;
    // park packed-bf16 copy in LDS for the mean phase.
    float dt[K_NEIGH], n2[K_NEIGH];
    #pragma unroll
    for (int r = 0; r < K_NEIGH; ++r) {
        const int    nidx = nb[r];           // wave-uniform -> s_load
        const float2 v = ((const float2*)(features + (size_t)nidx * D_FEAT))[lane];
        dt[r] = c2.x * v.x + c2.y * v.y;
        n2[r] = v.x * v.x + v.y * v.y;
        const __hip_bfloat162 h = __float22bfloat162_rn(v);
        s_rows[w][r * RSTRIDE + lane] = *(const unsigned*)&h;
    }

    // Fold: halves values-per-lane and lanes-per-value each step.
    #pragma unroll
    for (int o = 32; o >= 2; o >>= 1) {
        const bool up = (lane & o) != 0;
        #pragma unroll
        for (int r = 0; r < o / 2; ++r) {
            const float sd = up ? dt[r] : dt[r + o / 2];
            const float sn = up ? n2[r] : n2[r + o / 2];
            const float rd = __shfl_xor(sd, o);
            const float rn = __shfl_xor(sn, o);
            const float kd = up ? dt[r + o / 2] : dt[r];
            const float kn = up ? n2[r + o / 2] : n2[r];
            dt[r] = kd + rd;
            n2[r] = kn + rn;
        }
    }
    dt[0] += __shfl_xor(dt[0], 1);
    n2[0] += __shfl_xor(n2[0], 1);

    const int   myrow = lane >> 1;           // row whose sim this lane holds
    const float sim   = dt[0] / (cn * sqrtf(n2[0]));

    // Stable rank (matches lax.top_k tie-breaking): readlane broadcasts.
    int rank = 0;
    #pragma unroll
    for (int j = 0; j < K_NEIGH; ++j) {
        const float sj = readlane_f(sim, 2 * j);
        rank += (sj > sim || (sj == sim && j < myrow)) ? 1 : 0;
    }

    // Ballot has sel_r duplicated at bits 2r,2r+1 -> compress even bits.
    const unsigned long long bal = __ballot(rank < ns);
    unsigned long long x = bal & 0x5555555555555555ull;
    x = (x | (x >> 1))  & 0x3333333333333333ull;
    x = (x | (x >> 2))  & 0x0F0F0F0F0F0F0F0Full;
    x = (x | (x >> 4))  & 0x00FF00FF00FF00FFull;
    x = (x | (x >> 8))  & 0x0000FFFF0000FFFFull;
    x = (x | (x >> 16)) & 0x00000000FFFFFFFFull;
    unsigned mask = (unsigned)x;             // bit r = row r selected
    mask = __builtin_amdgcn_readfirstlane(mask);

    // Mean over selected rows from LDS (wave-uniform bit-scan, ~ns iters).
    float2 acc = make_float2(0.f, 0.f);
    while (mask) {
        const int r = __ffs(mask) - 1;
        mask &= mask - 1;
        const unsigned u = s_rows[w][r * RSTRIDE + lane];
        acc.x += __uint_as_float(u << 16);
        acc.y += __uint_as_float(u & 0xffff0000u);
    }
    const float nsf = (float)ns;
    float2 ov;
    ov.x = fmaxf(acc.x / nsf, 0.f);
    ov.y = fmaxf(acc.y / nsf, 0.f);
    ((float2*)(out + (size_t)b * D_FEAT))[lane] = ov;
}

extern "C" void kernel_launch(void* const* d_in, const int* in_sizes, int n_in,
                              void* d_out, int out_size, void* d_ws, size_t ws_size,
                              hipStream_t stream) {
    const float* features = (const float*)d_in[0];
    const int*   nodes    = (const int*)d_in[1];
    const int*   neighs   = (const int*)d_in[2];
    const int*   ns       = (const int*)d_in[3];
    float*       out      = (float*)d_out;

    const int batch  = in_sizes[1];            // 32768
    const int blocks = (batch + WPB - 1) / WPB;

    intra_agg_kernel<<<blocks, 256, 0, stream>>>(features, nodes, neighs, ns, out, batch);
}

// Round 5
// 240.761 us; speedup vs baseline: 1.2698x; 1.2698x over previous
//
#include <hip/hip_runtime.h>

#define K_NEIGH 32
#define D_FEAT  128

__device__ __forceinline__ float readlane_f(float v, int l) {
    return __int_as_float(__builtin_amdgcn_readlane(__float_as_int(v), l));
}

// One wave per batch element. Lane l owns dims [4*(l&31), 4*(l&31)+4) (float4).
// Lower half-wave processes rows 0..15, upper half rows 16..31: 16 load
// instructions cover all 32 rows (1KB/inst, fully coalesced). Dot/norm
// partials reduced with a 5-step fold within each 32-lane half (16 shuffles
// per quantity total). Top-k in fp32 (bit-exact vs reference). Mean phase
// re-loads only the ns selected rows, 2 per iteration (one per half).
__global__ __launch_bounds__(256, 6) void intra_agg_kernel(
    const float* __restrict__ features,
    const int*   __restrict__ nodes,
    const int*   __restrict__ neighs,
    const int*   __restrict__ num_sample_p,
    float*       __restrict__ out,
    int batch)
{
    const int tid  = blockIdx.x * blockDim.x + threadIdx.x;
    const int lane = threadIdx.x & 63;
    const int l32  = lane & 31;
    const int half = lane >> 5;
    int b = tid >> 6;
    if (b >= batch) return;
    b = __builtin_amdgcn_readfirstlane(b);

    const int  ns = *num_sample_p;
    const int* nb = neighs + (size_t)b * K_NEIGH;

    // Center fragment + ||center|| (5-step butterfly within each half).
    const int    cnode = nodes[b];
    const float4 c4 = ((const float4*)(features + (size_t)cnode * D_FEAT))[l32];
    float cc = c4.x*c4.x + c4.y*c4.y + c4.z*c4.z + c4.w*c4.w;
    #pragma unroll
    for (int m = 16; m >= 1; m >>= 1) cc += __shfl_xor(cc, m);
    const float cn = sqrtf(cc);

    // 16 rows per half: load (independent, coalesced), consume into partials.
    float dt[16], n2[16];
    #pragma unroll
    for (int i = 0; i < 16; ++i) {
        const int    nidx = nb[16 * half + i];   // wave-... half-uniform pair -> 2 segs
        const float4 v = ((const float4*)(features + (size_t)nidx * D_FEAT))[l32];
        dt[i] = c4.x*v.x + c4.y*v.y + c4.z*v.z + c4.w*v.w;
        n2[i] =  v.x*v.x +  v.y*v.y +  v.z*v.z +  v.w*v.w;
    }

    // Fold within each half: 16 values over 32 lanes -> lane l32 holds
    // its half's row (l32>>1) after the final xor-1 step.
    #pragma unroll
    for (int o = 16; o >= 2; o >>= 1) {
        const bool up = (lane & o) != 0;
        #pragma unroll
        for (int r = 0; r < o / 2; ++r) {
            const float sd = up ? dt[r] : dt[r + o / 2];
            const float sn = up ? n2[r] : n2[r + o / 2];
            const float rd = __shfl_xor(sd, o);
            const float rn = __shfl_xor(sn, o);
            const float kd = up ? dt[r + o / 2] : dt[r];
            const float kn = up ? n2[r + o / 2] : n2[r];
            dt[r] = kd + rd;
            n2[r] = kn + rn;
        }
    }
    dt[0] += __shfl_xor(dt[0], 1);
    n2[0] += __shfl_xor(n2[0], 1);

    const int   myrow = (half << 4) | (l32 >> 1);   // global row this lane holds
    const float sim   = dt[0] / (cn * sqrtf(n2[0]));

    // Stable rank (matches lax.top_k): row j lives at lane 2j.
    int rank = 0;
    #pragma unroll
    for (int j = 0; j < K_NEIGH; ++j) {
        const float sj = readlane_f(sim, 2 * j);
        rank += (sj > sim || (sj == sim && j < myrow)) ? 1 : 0;
    }

    // Ballot has row j's bit duplicated at 2j, 2j+1 -> compress even bits.
    const unsigned long long bal = __ballot(rank < ns);
    unsigned long long x = bal & 0x5555555555555555ull;
    x = (x | (x >> 1))  & 0x3333333333333333ull;
    x = (x | (x >> 2))  & 0x0F0F0F0F0F0F0F0Full;
    x = (x | (x >> 4))  & 0x00FF00FF00FF00FFull;
    x = (x | (x >> 8))  & 0x0000FFFF0000FFFFull;
    x = (x | (x >> 16)) & 0x00000000FFFFFFFFull;
    unsigned mask = __builtin_amdgcn_readfirstlane((unsigned)x);

    // Mean: re-load only selected rows, two per iteration (one per half).
    float4 acc = make_float4(0.f, 0.f, 0.f, 0.f);
    while (mask) {
        const int j0 = __ffs(mask) - 1; mask &= mask - 1;
        int   j1 = 0; float w1 = 0.f;
        if (mask) { j1 = __ffs(mask) - 1; mask &= mask - 1; w1 = 1.f; }
        const int   j = half ? j1 : j0;
        const float w = half ? w1 : 1.f;
        const int nidx = nb[j];
        const float4 r = ((const float4*)(features + (size_t)nidx * D_FEAT))[l32];
        acc.x = fmaf(r.x, w, acc.x);
        acc.y = fmaf(r.y, w, acc.y);
        acc.z = fmaf(r.z, w, acc.z);
        acc.w = fmaf(r.w, w, acc.w);
    }
    // Combine the two halves' partial sums.
    acc.x += __shfl_xor(acc.x, 32);
    acc.y += __shfl_xor(acc.y, 32);
    acc.z += __shfl_xor(acc.z, 32);
    acc.w += __shfl_xor(acc.w, 32);

    if (half == 0) {
        const float nsf = (float)ns;
        float4 o;
        o.x = fmaxf(acc.x / nsf, 0.f);
        o.y = fmaxf(acc.y / nsf, 0.f);
        o.z = fmaxf(acc.z / nsf, 0.f);
        o.w = fmaxf(acc.w / nsf, 0.f);
        ((float4*)(out + (size_t)b * D_FEAT))[l32] = o;
    }
}

extern "C" void kernel_launch(void* const* d_in, const int* in_sizes, int n_in,
                              void* d_out, int out_size, void* d_ws, size_t ws_size,
                              hipStream_t stream) {
    const float* features = (const float*)d_in[0];
    const int*   nodes    = (const int*)d_in[1];
    const int*   neighs   = (const int*)d_in[2];
    const int*   ns       = (const int*)d_in[3];
    float*       out      = (float*)d_out;

    const int batch  = in_sizes[1];            // 32768
    const int blocks = (batch + 3) / 4;        // 4 waves per 256-thread block

    intra_agg_kernel<<<blocks, 256, 0, stream>>>(features, nodes, neighs, ns, out, batch);
}